// Round 12
// baseline (309.356 us; speedup 1.0000x reference)
//
#include <hip/hip_runtime.h>
#include <hip/hip_bf16.h>
#include <math.h>

// Problem constants (NonLocalBlock): B=4, C=64, H=W=64 -> N=4096, CI=32
// Softmax trick: logits s[q][k] = x_q·x_k; shift by K[q] = |x_q|^2 (diagonal).
// Shifted diag = 0 -> denominator >= ~1 -> softmax is PURE exp + linear
// accumulation: partials across key-splits combine by plain addition.
//
// Session ledger: fills ~83us fixed; P-LDS-bounce flash ~32us; R10 P-in-regs
// spilled (59us); R11 spill-free P-in-regs = 43us but LATENCY-BOUND (V 8B
// loads sunk to use; VGPR 60 -> compiler serializes; MfmaUtil 14%).
// R12: buy TLP instead of fighting ILP -- kq split 4->8 doubles blocks/CU
// to the LDS/VGPR-admitted max (8 x 18.4KB = 147KB < 160KB; VGPR 60 <= 64).
// Grid 2048 = 8 blocks/CU x 256 CU; 32 waves/CU (HW max) overlap the
// per-wave stalls (m114 mechanism).
#define B_  4
#define C_  64
#define N_  4096
#define CI_ 32
#define KQ_ 8          // key-split count (was 4)

typedef __attribute__((ext_vector_type(8))) unsigned short u16x8;
typedef __attribute__((ext_vector_type(8))) __bf16        bf16x8;
typedef __attribute__((ext_vector_type(4))) __bf16        bf16x4;
typedef __attribute__((ext_vector_type(4))) float         f32x4;
typedef __attribute__((ext_vector_type(4))) short         short4b;

__device__ __forceinline__ unsigned short f2bf(float f) {
    union { float f; unsigned int i; } v; v.f = f;
    unsigned int r = v.i + 0x7FFFu + ((v.i >> 16) & 1u);
    return (unsigned short)(r >> 16);
}

// ---------------------------------------------------------------------------
// Kernel 1 (fused prep): per 64-n tile of one batch:
//   xT[b][n][c] (bf16)   <- transpose of x
//   gx[b][o][n] (bf16)   <- Wg x + bg
//   diag[b][n]  (f32)    <- |x_n|^2   (the softmax shift)
// Grid 256 = b(4) x ntile(64). Block 256.
// ---------------------------------------------------------------------------
__global__ __launch_bounds__(256) void k_prep(
    const float* __restrict__ x, const float* __restrict__ Wg,
    const float* __restrict__ bg, unsigned short* __restrict__ xT,
    unsigned short* __restrict__ gx, float* __restrict__ diag)
{
    __shared__ __align__(16) float tile[64][68];   // stride 68: rows 16B-aligned
    __shared__ float part[4][64][33];              // o 0..31 = gx, col 32 = diag
    const int t  = threadIdx.x;
    const int b  = blockIdx.x >> 6;
    const int n0 = (blockIdx.x & 63) * 64;

    #pragma unroll
    for (int pass = 0; pass < 4; ++pass) {
        int c   = (t >> 4) + pass * 16;
        int nl4 = (t & 15) * 4;
        float4 v = *(const float4*)(x + (size_t)(b * C_ + c) * N_ + n0 + nl4);
        *(float4*)&tile[c][nl4] = v;
    }
    __syncthreads();

    // (a) write xT (bf16 transpose), coalesced 128B per 4 lanes
    {
        const int n  = t >> 2;
        const int cc = (t & 3) * 16;
        u16x8 a, b2;
        #pragma unroll
        for (int j = 0; j < 8; ++j) a[j]  = f2bf(tile[cc + j][n]);
        #pragma unroll
        for (int j = 0; j < 8; ++j) b2[j] = f2bf(tile[cc + 8 + j][n]);
        unsigned short* dst = xT + (size_t)(b * N_ + n0 + n) * C_ + cc;
        *(u16x8*)dst       = a;
        *(u16x8*)(dst + 8) = b2;
    }
    // (b) gx partial + diag partial
    {
        const int nl = t & 63, cq = t >> 6;
        float acc[CI_];
        #pragma unroll
        for (int o = 0; o < CI_; ++o) acc[o] = 0.f;
        float dd = 0.f;
        #pragma unroll 4
        for (int cl = 0; cl < 16; ++cl) {
            int c = cq * 16 + cl;
            float xv = tile[c][nl];
            dd += xv * xv;
            #pragma unroll
            for (int o = 0; o < CI_; ++o) acc[o] += Wg[o * C_ + c] * xv;
        }
        #pragma unroll
        for (int o = 0; o < CI_; ++o) part[cq][nl][o] = acc[o];
        part[cq][nl][32] = dd;
    }
    __syncthreads();
    // (c) reduce + write gx
    {
        const int o = t >> 3, nr = (t & 7) * 8;
        u16x8 w;
        #pragma unroll
        for (int j = 0; j < 8; ++j) {
            int n = nr + j;
            float s = part[0][n][o] + part[1][n][o] + part[2][n][o] + part[3][n][o]
                    + bg[o];
            w[j] = f2bf(s);
        }
        *(u16x8*)(gx + (size_t)(b * CI_ + o) * N_ + n0 + nr) = w;
    }
    // (d) write diag
    if (t < 64)
        diag[(size_t)b * N_ + n0 + t] =
            part[0][t][32] + part[1][t][32] + part[2][t][32] + part[3][t][32];
}

// ---------------------------------------------------------------------------
// Kernel 2: flash partial, shift-softmax. Grid 2048 = b(4) x qtile(64) x kq(8).
// Block 256 = 4 waves; g = wave>>1 (256-key half), qh = wave&1 (32 queries).
// 8 tiles of 32 keys. Emits additive partials (Y[64q][32o], l[64q]).
//
// Structure = R11 (verified): K reg->LDS dbuf 2-phase pipeline, 1 barrier
// per tile; P kept in registers via the R10-verified layout identity:
//   QK:  mfma_f32_16x16x32_bf16, D[row=key=quad*4+r][col=q=li]
//   PV:  mfma_f32_16x16x16_bf16: A[m=li][k=quad*4+j] == QK's D lane mapping.
//   V:   4 x 8B B-fragments (K=16 layout) transient at-use (reg dbuf spills).
//   LDS: only K double-buffer (18432B; ym epilogue reuses it).
// ---------------------------------------------------------------------------
__device__ __forceinline__ f32x4 mfma16(bf16x8 a, bf16x8 b, f32x4 c) {
    return __builtin_amdgcn_mfma_f32_16x16x32_bf16(a, b, c, 0, 0, 0);
}

__device__ __forceinline__ f32x4 mfma1k(short4b a, short4b b, f32x4 c) {
#if __has_builtin(__builtin_amdgcn_mfma_f32_16x16x16bf16_1k)
    return __builtin_amdgcn_mfma_f32_16x16x16bf16_1k(a, b, c, 0, 0, 0);
#else
    f32x4 d = c;
    asm volatile("v_mfma_f32_16x16x16_bf16 %0, %1, %2, %0"
                 : "+v"(d) : "v"(a), "v"(b));
    return d;
#endif
}

// K-tile load (2 x 16B per thread) and store to a padded LDS buffer
#define KLOAD(kr, tT)                                                          \
    kr[0] = *(const u16x8*)(kSrc0 + (size_t)(tT) * (32 * C_));                 \
    kr[1] = *(const u16x8*)(kSrc1 + (size_t)(tT) * (32 * C_));

#define KSTORE(bufS, kr)                                                       \
    *(u16x8*)((bufS) + kDst0) = kr[0];                                         \
    *(u16x8*)((bufS) + kDst1) = kr[1];

// V B-fragments for K=16 PV: vr[kt][ot], 8B each (short4b bit-pun of bf16x4)
#define VLOAD(vr, tT)                                                          \
    vr[0][0] = *(const short4b*)(vb00 + (tT) * 32);                            \
    vr[0][1] = *(const short4b*)(vb01 + (tT) * 32);                            \
    vr[1][0] = *(const short4b*)(vb10 + (tT) * 32);                            \
    vr[1][1] = *(const short4b*)(vb11 + (tT) * 32);

// compute one 32-key tile: A from LDS buffer, V transient, P in regs
#define COMPUTE(ABUF, Vr)                                                      \
    {                                                                          \
        bf16x8 Af[2][2];                                                       \
        _Pragma("unroll")                                                      \
        for (int kt = 0; kt < 2; ++kt) {                                       \
            _Pragma("unroll")                                                  \
            for (int kc = 0; kc < 2; ++kc)                                     \
                Af[kt][kc] = *(const bf16x8*)((ABUF)                           \
                    + (g * 32 + kt * 16 + li) * 72 + kc * 32 + quad * 8);      \
        }                                                                      \
        f32x4 S[2][2];                                                         \
        _Pragma("unroll")                                                      \
        for (int kt = 0; kt < 2; ++kt) {                                       \
            _Pragma("unroll")                                                  \
            for (int qt = 0; qt < 2; ++qt) {                                   \
                f32x4 z = (f32x4){nKq[qt], nKq[qt], nKq[qt], nKq[qt]};         \
                z = mfma16(Af[kt][0], Qf[qt][0], z);                           \
                S[kt][qt] = mfma16(Af[kt][1], Qf[qt][1], z);                   \
            }                                                                  \
        }                                                                      \
        short4b Pa[2][2];                                                      \
        _Pragma("unroll")                                                      \
        for (int qt = 0; qt < 2; ++qt) {                                       \
            _Pragma("unroll")                                                  \
            for (int kt = 0; kt < 2; ++kt) {                                   \
                bf16x4 pb;                                                     \
                _Pragma("unroll")                                              \
                for (int r = 0; r < 4; ++r) {                                  \
                    float p = __expf(S[kt][qt][r]);                            \
                    lacc[qt] += p;                                             \
                    pb[r] = (__bf16)p;                                         \
                }                                                              \
                Pa[kt][qt] = *(short4b*)&pb;                                   \
            }                                                                  \
        }                                                                      \
        _Pragma("unroll")                                                      \
        for (int qt = 0; qt < 2; ++qt) {                                       \
            _Pragma("unroll")                                                  \
            for (int ot = 0; ot < 2; ++ot) {                                   \
                Yf[qt][ot] = mfma1k(Pa[0][qt], Vr[0][ot], Yf[qt][ot]);         \
                Yf[qt][ot] = mfma1k(Pa[1][qt], Vr[1][ot], Yf[qt][ot]);         \
            }                                                                  \
        }                                                                      \
    }

__global__ __launch_bounds__(256, 8) void k_flash(
    const unsigned short* __restrict__ xT, const unsigned short* __restrict__ gx,
    const float* __restrict__ diag,
    float* __restrict__ ypart, float* __restrict__ lpart)
{
    // LDS: xk0 [2g][32][72] 9216B | xk1 9216B = 18432B (ym epilogue reuses it)
    __shared__ __align__(16) char smem[18432];
    unsigned short* xk0 = (unsigned short*)smem;
    unsigned short* xk1 = (unsigned short*)(smem + 9216);

    const int tid  = threadIdx.x;
    const int wave = tid >> 6, lane = tid & 63;
    const int quad = lane >> 4, li = lane & 15;
    const int g = wave >> 1, qh = wave & 1;
    const int bi  = blockIdx.x;
    const int kq  = bi & 7;
    const int qtb = (bi >> 3) & 63;
    const int b   = bi >> 9;
    const int qw  = qtb * 64 + qh * 32;   // wave's first query
    const int u   = tid & 127;            // thread id within key-group

    const unsigned short* xb = xT + (size_t)b * N_ * C_;
    const unsigned short* gb = gx + (size_t)b * CI_ * N_;

    // per-lane softmax shift, negated (MFMA accumulator init)
    float nKq[2];
    #pragma unroll
    for (int qt = 0; qt < 2; ++qt)
        nKq[qt] = -diag[(size_t)b * N_ + qw + qt * 16 + li];

    // Q fragments (B-operand), resident in registers
    bf16x8 Qf[2][2];
    #pragma unroll
    for (int qt = 0; qt < 2; ++qt)
        #pragma unroll
        for (int kc = 0; kc < 2; ++kc)
            Qf[qt][kc] = *(const bf16x8*)(xb + (size_t)(qw + qt * 16 + li) * C_
                                          + kc * 32 + quad * 8);

    f32x4 Yf[2][2];
    #pragma unroll
    for (int qt = 0; qt < 2; ++qt)
        #pragma unroll
        for (int ot = 0; ot < 2; ++ot)
            Yf[qt][ot] = (f32x4){0.f, 0.f, 0.f, 0.f};
    float lacc[2] = {0.f, 0.f};

    const int keybase = kq * 512 + g * 256;           // this wave's compute keys
    const int gg = tid >> 7;                          // staging group (== g)
    const int sbase = kq * 512 + gg * 256;            // staged key range base

    // K staging addresses (per thread, 2 x 16B slices of the group's 4KB tile)
    const int cc0 = u * 2,      key0 = cc0 >> 3, cof0 = (cc0 & 7) * 8;
    const int cc1 = u * 2 + 1,  key1 = cc1 >> 3, cof1 = (cc1 & 7) * 8;
    const unsigned short* kSrc0 = xb + (size_t)(sbase + key0) * C_ + cof0;
    const unsigned short* kSrc1 = xb + (size_t)(sbase + key1) * C_ + cof1;
    const int kDst0 = (gg * 32 + key0) * 72 + cof0;
    const int kDst1 = (gg * 32 + key1) * 72 + cof1;

    // V B-fragment base pointers (K=16 layout): vbKT,OT
    const unsigned short* vb00 = gb + (size_t)(li) * N_      + keybase + quad * 4;
    const unsigned short* vb01 = gb + (size_t)(16 + li) * N_ + keybase + quad * 4;
    const unsigned short* vb10 = vb00 + 16;
    const unsigned short* vb11 = vb01 + 16;

    // ---- prologue ----
    u16x8 kA[2], kB[2];
    KLOAD(kA, 0)
    KLOAD(kB, 1)
    KSTORE(xk0, kA)            // K[0] -> buf0 (vmcnt wait on kA)
    KLOAD(kA, 2)               // K[2] in flight
    __syncthreads();           // buf0 ready

    #pragma unroll 1
    for (int t2 = 0; t2 < 4; ++t2) {
        const int te  = 2 * t2;
        const int nk0 = (te + 3 < 8) ? te + 3 : 7;    // clamped prefetch idx
        const int nk1 = (te + 4 < 8) ? te + 4 : 7;
        // ---- EVEN tile te: buf0 ----
        {
            KSTORE(xk1, kB)    // K[te+1] -> buf1 (kB issued a full tile ago)
            KLOAD(kB, nk0)     // issue-early: covered by this tile's compute
            short4b Vt[2][2];
            VLOAD(Vt, te)      // transient V; QK phase covers L1/L2 latency
            COMPUTE(xk0, Vt)
        }
        __syncthreads();
        // ---- ODD tile te+1: buf1 ----
        {
            KSTORE(xk0, kA)    // K[te+2] -> buf0
            KLOAD(kA, nk1)
            short4b Vt[2][2];
            VLOAD(Vt, te + 1)
            COMPUTE(xk1, Vt)
        }
        __syncthreads();
    }

    // finalize l: sum across quads (keys) -> every lane holds total for query li
    #pragma unroll
    for (int qt = 0; qt < 2; ++qt) {
        lacc[qt] += __shfl_xor(lacc[qt], 16, 64);
        lacc[qt] += __shfl_xor(lacc[qt], 32, 64);
    }

    // ---- combine the block's 2 key-groups (plain add) -> additive partial ----
    // (loop's final __syncthreads already synced; xk region is dead now)
    float* ym = (float*)smem;   // [4 wave][32 q][34]: o 0..31 = Y, col 32 = l

    #pragma unroll
    for (int qt = 0; qt < 2; ++qt) {
        #pragma unroll
        for (int ot = 0; ot < 2; ++ot)
            #pragma unroll
            for (int r = 0; r < 4; ++r)
                ym[(wave * 32 + qt * 16 + quad * 4 + r) * 34 + ot * 16 + li] = Yf[qt][ot][r];
        if (quad == 0)
            ym[(wave * 32 + qt * 16 + li) * 34 + 32] = lacc[qt];
    }
    __syncthreads();
    {
        const int q = tid >> 2, og = tid & 3;
        const int qh2 = q >> 5, ql = q & 31;
        const int w0 = qh2, w1 = 2 + qh2;   // same q-half, the two key-groups
        const size_t pbase = (size_t)(b * 64 + qtb) * KQ_ + kq;
        float* yp = ypart + pbase * 2048 + q * 32;
        #pragma unroll
        for (int j = 0; j < 8; ++j) {
            int o = og * 8 + j;
            yp[o] = ym[(w0 * 32 + ql) * 34 + o] + ym[(w1 * 32 + ql) * 34 + o];
        }
        if (og == 0)
            lpart[pbase * 64 + q] = ym[(w0 * 32 + ql) * 34 + 32]
                                  + ym[(w1 * 32 + ql) * 34 + 32];
    }
}

// ---------------------------------------------------------------------------
// Kernel 3: merge 8 key-eighth partials (plain add) + Wz epilogue + residual.
// Grid: 256 blocks = b x qtile. Block 256 threads.
// ---------------------------------------------------------------------------
__global__ __launch_bounds__(256) void k_merge(
    const float* __restrict__ ypart, const float* __restrict__ lpart,
    const float* __restrict__ x, const float* __restrict__ Wz,
    const float* __restrict__ bz, float* __restrict__ out)
{
    __shared__ float yfin[64][33];
    const int t   = threadIdx.x;
    const int b   = blockIdx.x >> 6;
    const int qtb = blockIdx.x & 63;
    const int q0  = qtb * 64;

    {
        const int q = t >> 2, og = t & 3;
        const size_t pb = (size_t)(b * 64 + qtb) * KQ_;
        float l = 0.f;
        #pragma unroll
        for (int kq = 0; kq < KQ_; ++kq)
            l += lpart[(pb + kq) * 64 + q];
        float inv = 1.f / l;
        #pragma unroll
        for (int j = 0; j < 8; ++j) {
            int o = og * 8 + j;
            float acc = 0.f;
            #pragma unroll
            for (int kq = 0; kq < KQ_; ++kq)
                acc += ypart[(pb + kq) * 2048 + q * 32 + o];
            yfin[q][o] = acc * inv;
        }
    }
    __syncthreads();
    {
        const int q = t & 63, c0 = t >> 6;
        #pragma unroll
        for (int i = 0; i < 16; ++i) {
            int cout = c0 + i * 4;
            float acc = bz[cout];
            #pragma unroll
            for (int o = 0; o < CI_; ++o)
                acc += Wz[cout * CI_ + o] * yfin[q][o];
            size_t oidx = (size_t)(b * C_ + cout) * N_ + q0 + q;
            out[oidx] = acc + x[oidx];
        }
    }
}

// ---------------------------------------------------------------------------
extern "C" void kernel_launch(void* const* d_in, const int* in_sizes, int n_in,
                              void* d_out, int out_size, void* d_ws, size_t ws_size,
                              hipStream_t stream) {
    (void)in_sizes; (void)n_in; (void)out_size; (void)ws_size;
    const float* x  = (const float*)d_in[0];
    const float* Wg = (const float*)d_in[1];
    const float* bg = (const float*)d_in[2];
    const float* Wz = (const float*)d_in[3];
    const float* bz = (const float*)d_in[4];
    float* out = (float*)d_out;

    // ws layout: xT 2MB | gx 1MB | diag 64KB | ypart 16MB | lpart 512KB (~19.6MB)
    unsigned short* xT = (unsigned short*)d_ws;
    unsigned short* gx = (unsigned short*)((char*)d_ws + 2097152);
    float* diag  = (float*)((char*)d_ws + 3145728);
    float* ypart = (float*)((char*)d_ws + 3211264);
    float* lpart = (float*)((char*)d_ws + 19988480);

    hipLaunchKernelGGL(k_prep,  dim3(B_ * (N_ / 64)),    dim3(256), 0, stream, x, Wg, bg, xT, gx, diag);
    hipLaunchKernelGGL(k_flash, dim3(B_ * 64 * KQ_),     dim3(256), 0, stream, xT, gx, diag, ypart, lpart);
    hipLaunchKernelGGL(k_merge, dim3(B_ * 64),           dim3(256), 0, stream, ypart, lpart, x, Wz, bz, out);
}

// Round 13
// 133.041 us; speedup vs baseline: 2.3253x; 2.3253x over previous
//
#include <hip/hip_runtime.h>
#include <hip/hip_bf16.h>
#include <math.h>

// Problem constants (NonLocalBlock): B=4, C=64, H=W=64 -> N=4096, CI=32
// Softmax trick: logits s[q][k] = x_q·x_k; shift by K[q] = |x_q|^2 (diagonal).
// Shifted diag = 0 -> denominator >= ~1 -> softmax is PURE exp + linear
// accumulation: partials across key-splits combine by plain addition.
//
// Session ledger: fills ~83us fixed; P-LDS-bounce flash ~32us; R11 P-in-regs
// spill-free = 43us latency-bound @4 blocks/CU (VGPR 60, MfmaUtil 14%).
// R12 tried KQ=8 + __launch_bounds__(256,8): occupancy DID hit 67% but the
// bound crushed regalloc to 32 VGPR -> ~1GB scratch traffic, 227us.
// R13 = R12 with launch_bounds REVERTED to (256,4): VGPR ~60 fits the
// 64-reg/8-wave tier on its own; LDS 18432B x 8 = 147KB < 160KB; the
// KQ=8 grid (2048 = 8 blocks/CU x 256 CU) supplies the residency.
#define B_  4
#define C_  64
#define N_  4096
#define CI_ 32
#define KQ_ 8          // key-split count

typedef __attribute__((ext_vector_type(8))) unsigned short u16x8;
typedef __attribute__((ext_vector_type(8))) __bf16        bf16x8;
typedef __attribute__((ext_vector_type(4))) __bf16        bf16x4;
typedef __attribute__((ext_vector_type(4))) float         f32x4;
typedef __attribute__((ext_vector_type(4))) short         short4b;

__device__ __forceinline__ unsigned short f2bf(float f) {
    union { float f; unsigned int i; } v; v.f = f;
    unsigned int r = v.i + 0x7FFFu + ((v.i >> 16) & 1u);
    return (unsigned short)(r >> 16);
}

// ---------------------------------------------------------------------------
// Kernel 1 (fused prep): per 64-n tile of one batch:
//   xT[b][n][c] (bf16)   <- transpose of x
//   gx[b][o][n] (bf16)   <- Wg x + bg
//   diag[b][n]  (f32)    <- |x_n|^2   (the softmax shift)
// Grid 256 = b(4) x ntile(64). Block 256.
// ---------------------------------------------------------------------------
__global__ __launch_bounds__(256) void k_prep(
    const float* __restrict__ x, const float* __restrict__ Wg,
    const float* __restrict__ bg, unsigned short* __restrict__ xT,
    unsigned short* __restrict__ gx, float* __restrict__ diag)
{
    __shared__ __align__(16) float tile[64][68];   // stride 68: rows 16B-aligned
    __shared__ float part[4][64][33];              // o 0..31 = gx, col 32 = diag
    const int t  = threadIdx.x;
    const int b  = blockIdx.x >> 6;
    const int n0 = (blockIdx.x & 63) * 64;

    #pragma unroll
    for (int pass = 0; pass < 4; ++pass) {
        int c   = (t >> 4) + pass * 16;
        int nl4 = (t & 15) * 4;
        float4 v = *(const float4*)(x + (size_t)(b * C_ + c) * N_ + n0 + nl4);
        *(float4*)&tile[c][nl4] = v;
    }
    __syncthreads();

    // (a) write xT (bf16 transpose), coalesced 128B per 4 lanes
    {
        const int n  = t >> 2;
        const int cc = (t & 3) * 16;
        u16x8 a, b2;
        #pragma unroll
        for (int j = 0; j < 8; ++j) a[j]  = f2bf(tile[cc + j][n]);
        #pragma unroll
        for (int j = 0; j < 8; ++j) b2[j] = f2bf(tile[cc + 8 + j][n]);
        unsigned short* dst = xT + (size_t)(b * N_ + n0 + n) * C_ + cc;
        *(u16x8*)dst       = a;
        *(u16x8*)(dst + 8) = b2;
    }
    // (b) gx partial + diag partial
    {
        const int nl = t & 63, cq = t >> 6;
        float acc[CI_];
        #pragma unroll
        for (int o = 0; o < CI_; ++o) acc[o] = 0.f;
        float dd = 0.f;
        #pragma unroll 4
        for (int cl = 0; cl < 16; ++cl) {
            int c = cq * 16 + cl;
            float xv = tile[c][nl];
            dd += xv * xv;
            #pragma unroll
            for (int o = 0; o < CI_; ++o) acc[o] += Wg[o * C_ + c] * xv;
        }
        #pragma unroll
        for (int o = 0; o < CI_; ++o) part[cq][nl][o] = acc[o];
        part[cq][nl][32] = dd;
    }
    __syncthreads();
    // (c) reduce + write gx
    {
        const int o = t >> 3, nr = (t & 7) * 8;
        u16x8 w;
        #pragma unroll
        for (int j = 0; j < 8; ++j) {
            int n = nr + j;
            float s = part[0][n][o] + part[1][n][o] + part[2][n][o] + part[3][n][o]
                    + bg[o];
            w[j] = f2bf(s);
        }
        *(u16x8*)(gx + (size_t)(b * CI_ + o) * N_ + n0 + nr) = w;
    }
    // (d) write diag
    if (t < 64)
        diag[(size_t)b * N_ + n0 + t] =
            part[0][t][32] + part[1][t][32] + part[2][t][32] + part[3][t][32];
}

// ---------------------------------------------------------------------------
// Kernel 2: flash partial, shift-softmax. Grid 2048 = b(4) x qtile(64) x kq(8).
// Block 256 = 4 waves; g = wave>>1 (256-key half), qh = wave&1 (32 queries).
// 8 tiles of 32 keys. Emits additive partials (Y[64q][32o], l[64q]).
//
// Structure = R11 (verified): K reg->LDS dbuf 2-phase pipeline, 1 barrier
// per tile; P kept in registers via the R10-verified layout identity:
//   QK:  mfma_f32_16x16x32_bf16, D[row=key=quad*4+r][col=q=li]
//   PV:  mfma_f32_16x16x16_bf16: A[m=li][k=quad*4+j] == QK's D lane mapping.
//   V:   4 x 8B B-fragments (K=16 layout) transient at-use (reg dbuf spills).
//   LDS: only K double-buffer (18432B; ym epilogue reuses it).
// launch_bounds (256,4): do NOT pin regalloc tighter (R12: (256,8) -> 32
// VGPR -> 1GB scratch). VGPR ~60 self-fits the 8-block/CU tier.
// ---------------------------------------------------------------------------
__device__ __forceinline__ f32x4 mfma16(bf16x8 a, bf16x8 b, f32x4 c) {
    return __builtin_amdgcn_mfma_f32_16x16x32_bf16(a, b, c, 0, 0, 0);
}

__device__ __forceinline__ f32x4 mfma1k(short4b a, short4b b, f32x4 c) {
#if __has_builtin(__builtin_amdgcn_mfma_f32_16x16x16bf16_1k)
    return __builtin_amdgcn_mfma_f32_16x16x16bf16_1k(a, b, c, 0, 0, 0);
#else
    f32x4 d = c;
    asm volatile("v_mfma_f32_16x16x16_bf16 %0, %1, %2, %0"
                 : "+v"(d) : "v"(a), "v"(b));
    return d;
#endif
}

// K-tile load (2 x 16B per thread) and store to a padded LDS buffer
#define KLOAD(kr, tT)                                                          \
    kr[0] = *(const u16x8*)(kSrc0 + (size_t)(tT) * (32 * C_));                 \
    kr[1] = *(const u16x8*)(kSrc1 + (size_t)(tT) * (32 * C_));

#define KSTORE(bufS, kr)                                                       \
    *(u16x8*)((bufS) + kDst0) = kr[0];                                         \
    *(u16x8*)((bufS) + kDst1) = kr[1];

// V B-fragments for K=16 PV: vr[kt][ot], 8B each (short4b bit-pun of bf16x4)
#define VLOAD(vr, tT)                                                          \
    vr[0][0] = *(const short4b*)(vb00 + (tT) * 32);                            \
    vr[0][1] = *(const short4b*)(vb01 + (tT) * 32);                            \
    vr[1][0] = *(const short4b*)(vb10 + (tT) * 32);                            \
    vr[1][1] = *(const short4b*)(vb11 + (tT) * 32);

// compute one 32-key tile: A from LDS buffer, V transient, P in regs
#define COMPUTE(ABUF, Vr)                                                      \
    {                                                                          \
        bf16x8 Af[2][2];                                                       \
        _Pragma("unroll")                                                      \
        for (int kt = 0; kt < 2; ++kt) {                                       \
            _Pragma("unroll")                                                  \
            for (int kc = 0; kc < 2; ++kc)                                     \
                Af[kt][kc] = *(const bf16x8*)((ABUF)                           \
                    + (g * 32 + kt * 16 + li) * 72 + kc * 32 + quad * 8);      \
        }                                                                      \
        f32x4 S[2][2];                                                         \
        _Pragma("unroll")                                                      \
        for (int kt = 0; kt < 2; ++kt) {                                       \
            _Pragma("unroll")                                                  \
            for (int qt = 0; qt < 2; ++qt) {                                   \
                f32x4 z = (f32x4){nKq[qt], nKq[qt], nKq[qt], nKq[qt]};         \
                z = mfma16(Af[kt][0], Qf[qt][0], z);                           \
                S[kt][qt] = mfma16(Af[kt][1], Qf[qt][1], z);                   \
            }                                                                  \
        }                                                                      \
        short4b Pa[2][2];                                                      \
        _Pragma("unroll")                                                      \
        for (int qt = 0; qt < 2; ++qt) {                                       \
            _Pragma("unroll")                                                  \
            for (int kt = 0; kt < 2; ++kt) {                                   \
                bf16x4 pb;                                                     \
                _Pragma("unroll")                                              \
                for (int r = 0; r < 4; ++r) {                                  \
                    float p = __expf(S[kt][qt][r]);                            \
                    lacc[qt] += p;                                             \
                    pb[r] = (__bf16)p;                                         \
                }                                                              \
                Pa[kt][qt] = *(short4b*)&pb;                                   \
            }                                                                  \
        }                                                                      \
        _Pragma("unroll")                                                      \
        for (int qt = 0; qt < 2; ++qt) {                                       \
            _Pragma("unroll")                                                  \
            for (int ot = 0; ot < 2; ++ot) {                                   \
                Yf[qt][ot] = mfma1k(Pa[0][qt], Vr[0][ot], Yf[qt][ot]);         \
                Yf[qt][ot] = mfma1k(Pa[1][qt], Vr[1][ot], Yf[qt][ot]);         \
            }                                                                  \
        }                                                                      \
    }

__global__ __launch_bounds__(256, 4) void k_flash(
    const unsigned short* __restrict__ xT, const unsigned short* __restrict__ gx,
    const float* __restrict__ diag,
    float* __restrict__ ypart, float* __restrict__ lpart)
{
    // LDS: xk0 [2g][32][72] 9216B | xk1 9216B = 18432B (ym epilogue reuses it)
    __shared__ __align__(16) char smem[18432];
    unsigned short* xk0 = (unsigned short*)smem;
    unsigned short* xk1 = (unsigned short*)(smem + 9216);

    const int tid  = threadIdx.x;
    const int wave = tid >> 6, lane = tid & 63;
    const int quad = lane >> 4, li = lane & 15;
    const int g = wave >> 1, qh = wave & 1;
    const int bi  = blockIdx.x;
    const int kq  = bi & 7;
    const int qtb = (bi >> 3) & 63;
    const int b   = bi >> 9;
    const int qw  = qtb * 64 + qh * 32;   // wave's first query
    const int u   = tid & 127;            // thread id within key-group

    const unsigned short* xb = xT + (size_t)b * N_ * C_;
    const unsigned short* gb = gx + (size_t)b * CI_ * N_;

    // per-lane softmax shift, negated (MFMA accumulator init)
    float nKq[2];
    #pragma unroll
    for (int qt = 0; qt < 2; ++qt)
        nKq[qt] = -diag[(size_t)b * N_ + qw + qt * 16 + li];

    // Q fragments (B-operand), resident in registers
    bf16x8 Qf[2][2];
    #pragma unroll
    for (int qt = 0; qt < 2; ++qt)
        #pragma unroll
        for (int kc = 0; kc < 2; ++kc)
            Qf[qt][kc] = *(const bf16x8*)(xb + (size_t)(qw + qt * 16 + li) * C_
                                          + kc * 32 + quad * 8);

    f32x4 Yf[2][2];
    #pragma unroll
    for (int qt = 0; qt < 2; ++qt)
        #pragma unroll
        for (int ot = 0; ot < 2; ++ot)
            Yf[qt][ot] = (f32x4){0.f, 0.f, 0.f, 0.f};
    float lacc[2] = {0.f, 0.f};

    const int keybase = kq * 512 + g * 256;           // this wave's compute keys
    const int gg = tid >> 7;                          // staging group (== g)
    const int sbase = kq * 512 + gg * 256;            // staged key range base

    // K staging addresses (per thread, 2 x 16B slices of the group's 4KB tile)
    const int cc0 = u * 2,      key0 = cc0 >> 3, cof0 = (cc0 & 7) * 8;
    const int cc1 = u * 2 + 1,  key1 = cc1 >> 3, cof1 = (cc1 & 7) * 8;
    const unsigned short* kSrc0 = xb + (size_t)(sbase + key0) * C_ + cof0;
    const unsigned short* kSrc1 = xb + (size_t)(sbase + key1) * C_ + cof1;
    const int kDst0 = (gg * 32 + key0) * 72 + cof0;
    const int kDst1 = (gg * 32 + key1) * 72 + cof1;

    // V B-fragment base pointers (K=16 layout): vbKT,OT
    const unsigned short* vb00 = gb + (size_t)(li) * N_      + keybase + quad * 4;
    const unsigned short* vb01 = gb + (size_t)(16 + li) * N_ + keybase + quad * 4;
    const unsigned short* vb10 = vb00 + 16;
    const unsigned short* vb11 = vb01 + 16;

    // ---- prologue ----
    u16x8 kA[2], kB[2];
    KLOAD(kA, 0)
    KLOAD(kB, 1)
    KSTORE(xk0, kA)            // K[0] -> buf0 (vmcnt wait on kA)
    KLOAD(kA, 2)               // K[2] in flight
    __syncthreads();           // buf0 ready

    #pragma unroll 1
    for (int t2 = 0; t2 < 4; ++t2) {
        const int te  = 2 * t2;
        const int nk0 = (te + 3 < 8) ? te + 3 : 7;    // clamped prefetch idx
        const int nk1 = (te + 4 < 8) ? te + 4 : 7;
        // ---- EVEN tile te: buf0 ----
        {
            KSTORE(xk1, kB)    // K[te+1] -> buf1 (kB issued a full tile ago)
            KLOAD(kB, nk0)     // issue-early: covered by this tile's compute
            short4b Vt[2][2];
            VLOAD(Vt, te)      // transient V; QK phase covers L1/L2 latency
            COMPUTE(xk0, Vt)
        }
        __syncthreads();
        // ---- ODD tile te+1: buf1 ----
        {
            KSTORE(xk0, kA)    // K[te+2] -> buf0
            KLOAD(kA, nk1)
            short4b Vt[2][2];
            VLOAD(Vt, te + 1)
            COMPUTE(xk1, Vt)
        }
        __syncthreads();
    }

    // finalize l: sum across quads (keys) -> every lane holds total for query li
    #pragma unroll
    for (int qt = 0; qt < 2; ++qt) {
        lacc[qt] += __shfl_xor(lacc[qt], 16, 64);
        lacc[qt] += __shfl_xor(lacc[qt], 32, 64);
    }

    // ---- combine the block's 2 key-groups (plain add) -> additive partial ----
    // (loop's final __syncthreads already synced; xk region is dead now)
    float* ym = (float*)smem;   // [4 wave][32 q][34]: o 0..31 = Y, col 32 = l

    #pragma unroll
    for (int qt = 0; qt < 2; ++qt) {
        #pragma unroll
        for (int ot = 0; ot < 2; ++ot)
            #pragma unroll
            for (int r = 0; r < 4; ++r)
                ym[(wave * 32 + qt * 16 + quad * 4 + r) * 34 + ot * 16 + li] = Yf[qt][ot][r];
        if (quad == 0)
            ym[(wave * 32 + qt * 16 + li) * 34 + 32] = lacc[qt];
    }
    __syncthreads();
    {
        const int q = tid >> 2, og = tid & 3;
        const int qh2 = q >> 5, ql = q & 31;
        const int w0 = qh2, w1 = 2 + qh2;   // same q-half, the two key-groups
        const size_t pbase = (size_t)(b * 64 + qtb) * KQ_ + kq;
        float* yp = ypart + pbase * 2048 + q * 32;
        #pragma unroll
        for (int j = 0; j < 8; ++j) {
            int o = og * 8 + j;
            yp[o] = ym[(w0 * 32 + ql) * 34 + o] + ym[(w1 * 32 + ql) * 34 + o];
        }
        if (og == 0)
            lpart[pbase * 64 + q] = ym[(w0 * 32 + ql) * 34 + 32]
                                  + ym[(w1 * 32 + ql) * 34 + 32];
    }
}

// ---------------------------------------------------------------------------
// Kernel 3: merge 8 key-eighth partials (plain add) + Wz epilogue + residual.
// Grid: 256 blocks = b x qtile. Block 256 threads.
// ---------------------------------------------------------------------------
__global__ __launch_bounds__(256) void k_merge(
    const float* __restrict__ ypart, const float* __restrict__ lpart,
    const float* __restrict__ x, const float* __restrict__ Wz,
    const float* __restrict__ bz, float* __restrict__ out)
{
    __shared__ float yfin[64][33];
    const int t   = threadIdx.x;
    const int b   = blockIdx.x >> 6;
    const int qtb = blockIdx.x & 63;
    const int q0  = qtb * 64;

    {
        const int q = t >> 2, og = t & 3;
        const size_t pb = (size_t)(b * 64 + qtb) * KQ_;
        float l = 0.f;
        #pragma unroll
        for (int kq = 0; kq < KQ_; ++kq)
            l += lpart[(pb + kq) * 64 + q];
        float inv = 1.f / l;
        #pragma unroll
        for (int j = 0; j < 8; ++j) {
            int o = og * 8 + j;
            float acc = 0.f;
            #pragma unroll
            for (int kq = 0; kq < KQ_; ++kq)
                acc += ypart[(pb + kq) * 2048 + q * 32 + o];
            yfin[q][o] = acc * inv;
        }
    }
    __syncthreads();
    {
        const int q = t & 63, c0 = t >> 6;
        #pragma unroll
        for (int i = 0; i < 16; ++i) {
            int cout = c0 + i * 4;
            float acc = bz[cout];
            #pragma unroll
            for (int o = 0; o < CI_; ++o)
                acc += Wz[cout * CI_ + o] * yfin[q][o];
            size_t oidx = (size_t)(b * C_ + cout) * N_ + q0 + q;
            out[oidx] = acc + x[oidx];
        }
    }
}

// ---------------------------------------------------------------------------
extern "C" void kernel_launch(void* const* d_in, const int* in_sizes, int n_in,
                              void* d_out, int out_size, void* d_ws, size_t ws_size,
                              hipStream_t stream) {
    (void)in_sizes; (void)n_in; (void)out_size; (void)ws_size;
    const float* x  = (const float*)d_in[0];
    const float* Wg = (const float*)d_in[1];
    const float* bg = (const float*)d_in[2];
    const float* Wz = (const float*)d_in[3];
    const float* bz = (const float*)d_in[4];
    float* out = (float*)d_out;

    // ws layout: xT 2MB | gx 1MB | diag 64KB | ypart 16MB | lpart 512KB (~19.6MB)
    unsigned short* xT = (unsigned short*)d_ws;
    unsigned short* gx = (unsigned short*)((char*)d_ws + 2097152);
    float* diag  = (float*)((char*)d_ws + 3145728);
    float* ypart = (float*)((char*)d_ws + 3211264);
    float* lpart = (float*)((char*)d_ws + 19988480);

    hipLaunchKernelGGL(k_prep,  dim3(B_ * (N_ / 64)),    dim3(256), 0, stream, x, Wg, bg, xT, gx, diag);
    hipLaunchKernelGGL(k_flash, dim3(B_ * 64 * KQ_),     dim3(256), 0, stream, xT, gx, diag, ypart, lpart);
    hipLaunchKernelGGL(k_merge, dim3(B_ * 64),           dim3(256), 0, stream, ypart, lpart, x, Wz, bz, out);
}

// Round 14
// 111.059 us; speedup vs baseline: 2.7855x; 1.1979x over previous
//
#include <hip/hip_runtime.h>
#include <hip/hip_bf16.h>
#include <math.h>

// Problem constants (NonLocalBlock): B=4, C=64, H=W=64 -> N=4096, CI=32
// Softmax trick: logits s[q][k] = x_q·x_k; shift by K[q] = |x_q|^2 (diagonal).
// Shifted diag = 0 -> denominator >= ~1 -> softmax = PURE exp + linear
// accumulation: key-split partials combine by plain addition.
//
// Session ledger (R0-R13): fills ~83us fixed harness cost; best verified =
// this 2-phase K-LDS pipeline @ flash ~32us (total 114.0). Failed: direct-
// global (52), clobber-pinned (74, spills), P-in-regs + transient V (43),
// + reg-dbuf V (59, spills), KQ=8 (47 / 227): ILP & TLP levers exhausted
// (occupancy HW-capped ~3 blocks/CU at VGPR~60; R12/R13 evidence).
// R14 = the verified 114.0us kernel + ONE change: XCD-aware block remap.
// k_prep scatters xT/gx across all 8 XCDs' L2s; flash re-reads are remote
// (~400-600cy, non-coherent per-XCD L2) inside the per-tile latency chain.
// Remap gives each XCD 2 (b,kq) combos -> its 128 blocks share ~1.3MB
// (Q 512K + K-slices 512K + gx 256K) < 4MB L2 -> local hits after first touch.
#define B_  4
#define C_  64
#define N_  4096
#define CI_ 32

typedef __attribute__((ext_vector_type(8))) unsigned short u16x8;
typedef __attribute__((ext_vector_type(8))) __bf16        bf16x8;
typedef __attribute__((ext_vector_type(4))) __bf16        bf16x4;
typedef __attribute__((ext_vector_type(4))) float         f32x4;

__device__ __forceinline__ unsigned short f2bf(float f) {
    union { float f; unsigned int i; } v; v.f = f;
    unsigned int r = v.i + 0x7FFFu + ((v.i >> 16) & 1u);
    return (unsigned short)(r >> 16);
}

// ---------------------------------------------------------------------------
// Kernel 1 (fused prep): per 64-n tile of one batch:
//   xT[b][n][c] (bf16)   <- transpose of x
//   gx[b][o][n] (bf16)   <- Wg x + bg
//   diag[b][n]  (f32)    <- |x_n|^2   (the softmax shift)
// Grid 256 = b(4) x ntile(64). Block 256.
// ---------------------------------------------------------------------------
__global__ __launch_bounds__(256) void k_prep(
    const float* __restrict__ x, const float* __restrict__ Wg,
    const float* __restrict__ bg, unsigned short* __restrict__ xT,
    unsigned short* __restrict__ gx, float* __restrict__ diag)
{
    __shared__ __align__(16) float tile[64][68];   // stride 68: rows 16B-aligned
    __shared__ float part[4][64][33];              // o 0..31 = gx, col 32 = diag
    const int t  = threadIdx.x;
    const int b  = blockIdx.x >> 6;
    const int n0 = (blockIdx.x & 63) * 64;

    #pragma unroll
    for (int pass = 0; pass < 4; ++pass) {
        int c   = (t >> 4) + pass * 16;
        int nl4 = (t & 15) * 4;
        float4 v = *(const float4*)(x + (size_t)(b * C_ + c) * N_ + n0 + nl4);
        *(float4*)&tile[c][nl4] = v;
    }
    __syncthreads();

    // (a) write xT (bf16 transpose), coalesced 128B per 4 lanes
    {
        const int n  = t >> 2;
        const int cc = (t & 3) * 16;
        u16x8 a, b2;
        #pragma unroll
        for (int j = 0; j < 8; ++j) a[j]  = f2bf(tile[cc + j][n]);
        #pragma unroll
        for (int j = 0; j < 8; ++j) b2[j] = f2bf(tile[cc + 8 + j][n]);
        unsigned short* dst = xT + (size_t)(b * N_ + n0 + n) * C_ + cc;
        *(u16x8*)dst       = a;
        *(u16x8*)(dst + 8) = b2;
    }
    // (b) gx partial + diag partial
    {
        const int nl = t & 63, cq = t >> 6;
        float acc[CI_];
        #pragma unroll
        for (int o = 0; o < CI_; ++o) acc[o] = 0.f;
        float dd = 0.f;
        #pragma unroll 4
        for (int cl = 0; cl < 16; ++cl) {
            int c = cq * 16 + cl;
            float xv = tile[c][nl];
            dd += xv * xv;
            #pragma unroll
            for (int o = 0; o < CI_; ++o) acc[o] += Wg[o * C_ + c] * xv;
        }
        #pragma unroll
        for (int o = 0; o < CI_; ++o) part[cq][nl][o] = acc[o];
        part[cq][nl][32] = dd;
    }
    __syncthreads();
    // (c) reduce + write gx
    {
        const int o = t >> 3, nr = (t & 7) * 8;
        u16x8 w;
        #pragma unroll
        for (int j = 0; j < 8; ++j) {
            int n = nr + j;
            float s = part[0][n][o] + part[1][n][o] + part[2][n][o] + part[3][n][o]
                    + bg[o];
            w[j] = f2bf(s);
        }
        *(u16x8*)(gx + (size_t)(b * CI_ + o) * N_ + n0 + nr) = w;
    }
    // (d) write diag
    if (t < 64)
        diag[(size_t)b * N_ + n0 + t] =
            part[0][t][32] + part[1][t][32] + part[2][t][32] + part[3][t][32];
}

// ---------------------------------------------------------------------------
// Kernel 2: flash partial, shift-softmax. Grid 1024 = b(4) x qtile(64) x kq(4),
// XCD-REMAPPED. Block 256 = 4 waves; g = wave>>1 (512-key half), qh = wave&1
// (32 queries). 16 tiles of 32 keys. Emits additive partials per block.
//
// 2-PHASE PIPELINE (verified @ 114.0us total): K cooperative reg->LDS double
// buffer (1 barrier per tile pins the schedule + enables cross-wave K share);
// V (gx layout == B-operand layout) register double-buffered 16B loads; P
// bounced through LDS (wave-private). Loads issued after compute, before the
// barrier (R4-verified ordering).
//
// XCD remap (assumes round-robin dispatch->XCD, perf-only): xcd = bi&7;
// combo = xcd*2 + ((bi>>3)&1) in 0..15 -> (b = combo>>2, kq = combo&3);
// qtb = bi>>4. Bijective over 1024 blocks. Each XCD's 128 blocks then share
// one b's Q rows + 2 kq K-slices + gx(b) ~= 1.3MB -> local-L2 resident.
//
// MFMA 16x16x32 bf16 layouts (verified on HW):
//   A: [m=lane&15][k=quad*8+j]  B: [k=quad*8+j][n=lane&15]  D: row=quad*4+r, col=lane&15
// ---------------------------------------------------------------------------
__device__ __forceinline__ f32x4 mfma16(bf16x8 a, bf16x8 b, f32x4 c) {
    return __builtin_amdgcn_mfma_f32_16x16x32_bf16(a, b, c, 0, 0, 0);
}

// K-tile load (2 x 16B per thread) and store to a padded LDS buffer
#define KLOAD(kr, tT)                                                          \
    kr[0] = *(const u16x8*)(kSrc0 + (size_t)(tT) * (32 * C_));                 \
    kr[1] = *(const u16x8*)(kSrc1 + (size_t)(tT) * (32 * C_));

#define KSTORE(bufS, kr)                                                       \
    *(u16x8*)((bufS) + kDst0) = kr[0];                                         \
    *(u16x8*)((bufS) + kDst1) = kr[1];

#define VLOAD(vr, tT)                                                          \
    vr[0] = *(const bf16x8*)(bBase0 + (tT) * 32);                              \
    vr[1] = *(const bf16x8*)(bBase1 + (tT) * 32);

// compute one 32-key tile: A from LDS buffer, V from registers
#define COMPUTE(ABUF, Vr)                                                      \
    {                                                                          \
        bf16x8 Af[2][2];                                                       \
        _Pragma("unroll")                                                      \
        for (int kt = 0; kt < 2; ++kt) {                                       \
            _Pragma("unroll")                                                  \
            for (int kc = 0; kc < 2; ++kc)                                     \
                Af[kt][kc] = *(const bf16x8*)((ABUF)                           \
                    + (g * 32 + kt * 16 + li) * 72 + kc * 32 + quad * 8);      \
        }                                                                      \
        f32x4 S[2][2];                                                         \
        _Pragma("unroll")                                                      \
        for (int kt = 0; kt < 2; ++kt) {                                       \
            _Pragma("unroll")                                                  \
            for (int qt = 0; qt < 2; ++qt) {                                   \
                f32x4 z = (f32x4){nKq[qt], nKq[qt], nKq[qt], nKq[qt]};         \
                z = mfma16(Af[kt][0], Qf[qt][0], z);                           \
                S[kt][qt] = mfma16(Af[kt][1], Qf[qt][1], z);                   \
            }                                                                  \
        }                                                                      \
        _Pragma("unroll")                                                      \
        for (int qt = 0; qt < 2; ++qt) {                                       \
            _Pragma("unroll")                                                  \
            for (int kt = 0; kt < 2; ++kt) {                                   \
                bf16x4 pb;                                                     \
                _Pragma("unroll")                                              \
                for (int r = 0; r < 4; ++r) {                                  \
                    float p = __expf(S[kt][qt][r]);                            \
                    lacc[qt] += p;                                             \
                    pb[r] = (__bf16)p;                                         \
                }                                                              \
                *(bf16x4*)(pW + qt * 640 + kt * 16) = pb;                      \
            }                                                                  \
        }                                                                      \
        bf16x8 Ap[2];                                                          \
        _Pragma("unroll")                                                      \
        for (int qt = 0; qt < 2; ++qt)                                         \
            Ap[qt] = *(const bf16x8*)(pR + qt * 640);                          \
        _Pragma("unroll")                                                      \
        for (int qt = 0; qt < 2; ++qt) {                                       \
            _Pragma("unroll")                                                  \
            for (int ot = 0; ot < 2; ++ot)                                     \
                Yf[qt][ot] = mfma16(Ap[qt], Vr[ot], Yf[qt][ot]);               \
        }                                                                      \
    }

__global__ __launch_bounds__(256, 4) void k_flash(
    const unsigned short* __restrict__ xT, const unsigned short* __restrict__ gx,
    const float* __restrict__ diag,
    float* __restrict__ ypart, float* __restrict__ lpart)
{
    // LDS: xk0 [2g][32][72] 9216B | xk1 9216B | Pl [4][32][40] 10240B = 28672B
    __shared__ __align__(16) char smem[28672];
    unsigned short* xk0 = (unsigned short*)smem;
    unsigned short* xk1 = (unsigned short*)(smem + 9216);
    unsigned short* Pl  = (unsigned short*)(smem + 18432);

    const int tid  = threadIdx.x;
    const int wave = tid >> 6, lane = tid & 63;
    const int quad = lane >> 4, li = lane & 15;
    const int g = wave >> 1, qh = wave & 1;
    // ---- XCD-aware remap (bijective over 1024 blocks) ----
    const int bi    = blockIdx.x;
    const int xcd   = bi & 7;
    const int combo = xcd * 2 + ((bi >> 3) & 1);   // 0..15 = (b,kq)
    const int b     = combo >> 2;
    const int kq    = combo & 3;
    const int qtb   = bi >> 4;                     // 0..63
    const int qw  = qtb * 64 + qh * 32;   // wave's first query
    const int u   = tid & 127;            // thread id within key-group

    const unsigned short* xb = xT + (size_t)b * N_ * C_;
    const unsigned short* gb = gx + (size_t)b * CI_ * N_;

    // per-lane softmax shift, negated (MFMA accumulator init)
    float nKq[2];
    #pragma unroll
    for (int qt = 0; qt < 2; ++qt)
        nKq[qt] = -diag[(size_t)b * N_ + qw + qt * 16 + li];

    // Q fragments (B-operand), resident in registers
    bf16x8 Qf[2][2];
    #pragma unroll
    for (int qt = 0; qt < 2; ++qt)
        #pragma unroll
        for (int kc = 0; kc < 2; ++kc)
            Qf[qt][kc] = *(const bf16x8*)(xb + (size_t)(qw + qt * 16 + li) * C_
                                          + kc * 32 + quad * 8);

    f32x4 Yf[2][2];
    #pragma unroll
    for (int qt = 0; qt < 2; ++qt)
        #pragma unroll
        for (int ot = 0; ot < 2; ++ot)
            Yf[qt][ot] = (f32x4){0.f, 0.f, 0.f, 0.f};
    float lacc[2] = {0.f, 0.f};

    const int keybase = kq * 1024 + g * 512;          // this wave's compute keys
    const int gg = tid >> 7;                          // staging group (== g)
    const int sbase = kq * 1024 + gg * 512;           // staged key range base

    // K staging addresses (per thread, 2 x 16B slices of the group's 4KB tile)
    const int cc0 = u * 2,      key0 = cc0 >> 3, cof0 = (cc0 & 7) * 8;
    const int cc1 = u * 2 + 1,  key1 = cc1 >> 3, cof1 = (cc1 & 7) * 8;
    const unsigned short* kSrc0 = xb + (size_t)(sbase + key0) * C_ + cof0;
    const unsigned short* kSrc1 = xb + (size_t)(sbase + key1) * C_ + cof1;
    const int kDst0 = (gg * 32 + key0) * 72 + cof0;
    const int kDst1 = (gg * 32 + key1) * 72 + cof1;

    // V fragment pointers (B-operand layout == gx layout)
    const unsigned short* bBase0 = gb + (size_t)(li) * N_      + keybase + quad * 8;
    const unsigned short* bBase1 = gb + (size_t)(16 + li) * N_ + keybase + quad * 8;

    // P bounce (within-wave only; same-wave LDS ordering suffices)
    unsigned short*       pW = Pl + (wave * 32 + li) * 40 + quad * 4;
    const unsigned short* pR = Pl + (wave * 32 + li) * 40 + quad * 8;

    // ---- prologue ----
    u16x8  kA[2], kB[2];
    bf16x8 vA[2], vB[2];
    KLOAD(kA, 0) VLOAD(vA, 0)
    KLOAD(kB, 1) VLOAD(vB, 1)
    KSTORE(xk0, kA)            // K[0] -> buf0 (vmcnt wait on kA)
    KLOAD(kA, 2)               // K[2] in flight
    __syncthreads();           // buf0 ready

    #pragma unroll 1
    for (int t2 = 0; t2 < 8; ++t2) {
        const int te = 2 * t2;
        // ---- EVEN tile te: buf0 + vA ----
        KSTORE(xk1, kB)                        // K[te+1] -> buf1 (readers done)
        COMPUTE(xk0, vA)
        { const int nk = (te + 3 < 16) ? te + 3 : 15; KLOAD(kB, nk) }
        { const int nv = (te + 2 < 16) ? te + 2 : 15; VLOAD(vA, nv) }
        __syncthreads();                       // buf1 ready
        // ---- ODD tile te+1: buf1 + vB ----
        if (t2 < 7) { KSTORE(xk0, kA) }        // K[te+2] -> buf0
        COMPUTE(xk1, vB)
        { const int nk = (te + 4 < 16) ? te + 4 : 15; KLOAD(kA, nk) }
        { const int nv = (te + 3 < 16) ? te + 3 : 15; VLOAD(vB, nv) }
        __syncthreads();                       // buf0 ready
    }

    // finalize l: sum across quads (keys) -> every lane holds total for query li
    #pragma unroll
    for (int qt = 0; qt < 2; ++qt) {
        lacc[qt] += __shfl_xor(lacc[qt], 16, 64);
        lacc[qt] += __shfl_xor(lacc[qt], 32, 64);
    }

    // ---- combine the block's 2 key-groups (plain add) -> additive partial ----
    float* ym = (float*)smem;   // [4 wave][32 q][34]: o 0..31 = Y, col 32 = l

    #pragma unroll
    for (int qt = 0; qt < 2; ++qt) {
        #pragma unroll
        for (int ot = 0; ot < 2; ++ot)
            #pragma unroll
            for (int r = 0; r < 4; ++r)
                ym[(wave * 32 + qt * 16 + quad * 4 + r) * 34 + ot * 16 + li] = Yf[qt][ot][r];
        if (quad == 0)
            ym[(wave * 32 + qt * 16 + li) * 34 + 32] = lacc[qt];
    }
    __syncthreads();
    {
        const int q = tid >> 2, og = tid & 3;
        const int qh2 = q >> 5, ql = q & 31;
        const int w0 = qh2, w1 = 2 + qh2;   // same q-half, the two key-groups
        const size_t pbase = (size_t)(b * 64 + qtb) * 4 + kq;
        float* yp = ypart + pbase * 2048 + q * 32;
        #pragma unroll
        for (int j = 0; j < 8; ++j) {
            int o = og * 8 + j;
            yp[o] = ym[(w0 * 32 + ql) * 34 + o] + ym[(w1 * 32 + ql) * 34 + o];
        }
        if (og == 0)
            lpart[pbase * 64 + q] = ym[(w0 * 32 + ql) * 34 + 32]
                                  + ym[(w1 * 32 + ql) * 34 + 32];
    }
}

// ---------------------------------------------------------------------------
// Kernel 3: merge 4 key-quarter partials (plain add) + Wz epilogue + residual.
// Grid: 256 blocks = b x qtile. Block 256 threads.
// ---------------------------------------------------------------------------
__global__ __launch_bounds__(256) void k_merge(
    const float* __restrict__ ypart, const float* __restrict__ lpart,
    const float* __restrict__ x, const float* __restrict__ Wz,
    const float* __restrict__ bz, float* __restrict__ out)
{
    __shared__ float yfin[64][33];
    const int t   = threadIdx.x;
    const int b   = blockIdx.x >> 6;
    const int qtb = blockIdx.x & 63;
    const int q0  = qtb * 64;

    {
        const int q = t >> 2, og = t & 3;
        const size_t pb = (size_t)(b * 64 + qtb) * 4;
        float l = lpart[(pb + 0) * 64 + q] + lpart[(pb + 1) * 64 + q]
                + lpart[(pb + 2) * 64 + q] + lpart[(pb + 3) * 64 + q];
        float inv = 1.f / l;
        #pragma unroll
        for (int j = 0; j < 8; ++j) {
            int o = og * 8 + j;
            float acc = 0.f;
            #pragma unroll
            for (int kq = 0; kq < 4; ++kq)
                acc += ypart[(pb + kq) * 2048 + q * 32 + o];
            yfin[q][o] = acc * inv;
        }
    }
    __syncthreads();
    {
        const int q = t & 63, c0 = t >> 6;
        #pragma unroll
        for (int i = 0; i < 16; ++i) {
            int cout = c0 + i * 4;
            float acc = bz[cout];
            #pragma unroll
            for (int o = 0; o < CI_; ++o)
                acc += Wz[cout * CI_ + o] * yfin[q][o];
            size_t oidx = (size_t)(b * C_ + cout) * N_ + q0 + q;
            out[oidx] = acc + x[oidx];
        }
    }
}

// ---------------------------------------------------------------------------
extern "C" void kernel_launch(void* const* d_in, const int* in_sizes, int n_in,
                              void* d_out, int out_size, void* d_ws, size_t ws_size,
                              hipStream_t stream) {
    (void)in_sizes; (void)n_in; (void)out_size; (void)ws_size;
    const float* x  = (const float*)d_in[0];
    const float* Wg = (const float*)d_in[1];
    const float* bg = (const float*)d_in[2];
    const float* Wz = (const float*)d_in[3];
    const float* bz = (const float*)d_in[4];
    float* out = (float*)d_out;

    // ws layout: xT 2MB | gx 1MB | diag 64KB | ypart 8MB | lpart 256KB (~11.3MB)
    unsigned short* xT = (unsigned short*)d_ws;
    unsigned short* gx = (unsigned short*)((char*)d_ws + 2097152);
    float* diag  = (float*)((char*)d_ws + 3145728);
    float* ypart = (float*)((char*)d_ws + 3211264);
    float* lpart = (float*)((char*)d_ws + 11599872);

    hipLaunchKernelGGL(k_prep,  dim3(B_ * (N_ / 64)),    dim3(256), 0, stream, x, Wg, bg, xT, gx, diag);
    hipLaunchKernelGGL(k_flash, dim3(B_ * 64 * 4),       dim3(256), 0, stream, xT, gx, diag, ypart, lpart);
    hipLaunchKernelGGL(k_merge, dim3(B_ * 64),           dim3(256), 0, stream, ypart, lpart, x, Wz, bz, out);
}

// Round 15
// 110.898 us; speedup vs baseline: 2.7895x; 1.0015x over previous
//
#include <hip/hip_runtime.h>
#include <hip/hip_bf16.h>
#include <math.h>

// Problem constants (NonLocalBlock): B=4, C=64, H=W=64 -> N=4096, CI=32
// Softmax trick: logits s[q][k] = x_q·x_k; shift by K[q] = |x_q|^2 (diagonal).
// Shifted diag = 0 -> denominator >= ~1 -> softmax = PURE exp + linear
// accumulation: key-split partials combine by plain addition.
//
// Session ledger (R0-R14): fills ~83us fixed; R14 verified best = 111.1us
// (2-phase K-LDS pipeline + XCD remap; flash ~27us). R15 = R14 + ONE change:
// P DOUBLE-BUFFER, PV DEFERRED ONE TILE (T15 idea through LDS). Phase t:
// QK[t]+exp[t]+write P[t]->Pl[t&1], then PV[t-1] from Pl[(t-1)&1] whose
// ds_write retired a full phase ago -> the per-tile serial chain loses the
// ds_write->lgkmcnt->ds_read segment; PV overlaps exp on the MFMA pipe.
// (R8: this round trip was the schedule-invariant ~32us plateau's chain;
// R10/R11 killed it via P-in-regs but died on register pressure instead.)
#define B_  4
#define C_  64
#define N_  4096
#define CI_ 32

typedef __attribute__((ext_vector_type(8))) unsigned short u16x8;
typedef __attribute__((ext_vector_type(8))) __bf16        bf16x8;
typedef __attribute__((ext_vector_type(4))) __bf16        bf16x4;
typedef __attribute__((ext_vector_type(4))) float         f32x4;

__device__ __forceinline__ unsigned short f2bf(float f) {
    union { float f; unsigned int i; } v; v.f = f;
    unsigned int r = v.i + 0x7FFFu + ((v.i >> 16) & 1u);
    return (unsigned short)(r >> 16);
}

// ---------------------------------------------------------------------------
// Kernel 1 (fused prep): per 64-n tile of one batch:
//   xT[b][n][c] (bf16)   <- transpose of x
//   gx[b][o][n] (bf16)   <- Wg x + bg
//   diag[b][n]  (f32)    <- |x_n|^2   (the softmax shift)
// Grid 256 = b(4) x ntile(64). Block 256.
// ---------------------------------------------------------------------------
__global__ __launch_bounds__(256) void k_prep(
    const float* __restrict__ x, const float* __restrict__ Wg,
    const float* __restrict__ bg, unsigned short* __restrict__ xT,
    unsigned short* __restrict__ gx, float* __restrict__ diag)
{
    __shared__ __align__(16) float tile[64][68];   // stride 68: rows 16B-aligned
    __shared__ float part[4][64][33];              // o 0..31 = gx, col 32 = diag
    const int t  = threadIdx.x;
    const int b  = blockIdx.x >> 6;
    const int n0 = (blockIdx.x & 63) * 64;

    #pragma unroll
    for (int pass = 0; pass < 4; ++pass) {
        int c   = (t >> 4) + pass * 16;
        int nl4 = (t & 15) * 4;
        float4 v = *(const float4*)(x + (size_t)(b * C_ + c) * N_ + n0 + nl4);
        *(float4*)&tile[c][nl4] = v;
    }
    __syncthreads();

    // (a) write xT (bf16 transpose), coalesced 128B per 4 lanes
    {
        const int n  = t >> 2;
        const int cc = (t & 3) * 16;
        u16x8 a, b2;
        #pragma unroll
        for (int j = 0; j < 8; ++j) a[j]  = f2bf(tile[cc + j][n]);
        #pragma unroll
        for (int j = 0; j < 8; ++j) b2[j] = f2bf(tile[cc + 8 + j][n]);
        unsigned short* dst = xT + (size_t)(b * N_ + n0 + n) * C_ + cc;
        *(u16x8*)dst       = a;
        *(u16x8*)(dst + 8) = b2;
    }
    // (b) gx partial + diag partial
    {
        const int nl = t & 63, cq = t >> 6;
        float acc[CI_];
        #pragma unroll
        for (int o = 0; o < CI_; ++o) acc[o] = 0.f;
        float dd = 0.f;
        #pragma unroll 4
        for (int cl = 0; cl < 16; ++cl) {
            int c = cq * 16 + cl;
            float xv = tile[c][nl];
            dd += xv * xv;
            #pragma unroll
            for (int o = 0; o < CI_; ++o) acc[o] += Wg[o * C_ + c] * xv;
        }
        #pragma unroll
        for (int o = 0; o < CI_; ++o) part[cq][nl][o] = acc[o];
        part[cq][nl][32] = dd;
    }
    __syncthreads();
    // (c) reduce + write gx
    {
        const int o = t >> 3, nr = (t & 7) * 8;
        u16x8 w;
        #pragma unroll
        for (int j = 0; j < 8; ++j) {
            int n = nr + j;
            float s = part[0][n][o] + part[1][n][o] + part[2][n][o] + part[3][n][o]
                    + bg[o];
            w[j] = f2bf(s);
        }
        *(u16x8*)(gx + (size_t)(b * CI_ + o) * N_ + n0 + nr) = w;
    }
    // (d) write diag
    if (t < 64)
        diag[(size_t)b * N_ + n0 + t] =
            part[0][t][32] + part[1][t][32] + part[2][t][32] + part[3][t][32];
}

// ---------------------------------------------------------------------------
// Kernel 2: flash partial, shift-softmax. Grid 1024 = b(4) x qtile(64) x kq(4),
// XCD-REMAPPED (R14-verified, +4-5us). Block 256 = 4 waves; g = wave>>1
// (512-key half), qh = wave&1 (32 queries). 16 tiles of 32 keys.
//
// 2-PHASE K PIPELINE + DEFERRED-PV P DOUBLE-BUFFER:
//   K: cooperative reg->LDS dbuf (xk0/xk1), 1 barrier per tile.
//   P: wave-private LDS dbuf (Pl0/Pl1). Phase t: QK[t]+exp -> Pl[t&1];
//      PV[t-1] from Pl[(t-1)&1] (write retired a full phase ago -> no
//      lgkmcnt stall; PV overlaps next QK's exp chain).
//   V: register sets vA (even tiles) / vB (odd), reloaded AFTER their
//      deferred PV consumes them (still >= 1 phase of lead).
//   XCD remap: xcd=bi&7; combo=xcd*2+((bi>>3)&1) -> (b,kq); qtb=bi>>4.
//
// MFMA 16x16x32 bf16 layouts (verified on HW):
//   A: [m=lane&15][k=quad*8+j]  B: [k=quad*8+j][n=lane&15]  D: row=quad*4+r, col=lane&15
// ---------------------------------------------------------------------------
__device__ __forceinline__ f32x4 mfma16(bf16x8 a, bf16x8 b, f32x4 c) {
    return __builtin_amdgcn_mfma_f32_16x16x32_bf16(a, b, c, 0, 0, 0);
}

// K-tile load (2 x 16B per thread) and store to a padded LDS buffer
#define KLOAD(kr, tT)                                                          \
    kr[0] = *(const u16x8*)(kSrc0 + (size_t)(tT) * (32 * C_));                 \
    kr[1] = *(const u16x8*)(kSrc1 + (size_t)(tT) * (32 * C_));

#define KSTORE(bufS, kr)                                                       \
    *(u16x8*)((bufS) + kDst0) = kr[0];                                         \
    *(u16x8*)((bufS) + kDst1) = kr[1];

#define VLOAD(vr, tT)                                                          \
    vr[0] = *(const bf16x8*)(bBase0 + (tT) * 32);                              \
    vr[1] = *(const bf16x8*)(bBase1 + (tT) * 32);

// QK phase: A from LDS buffer, exp, write P to PWp (wave-private LDS)
#define QKPH(ABUF, PWp)                                                        \
    {                                                                          \
        bf16x8 Af[2][2];                                                       \
        _Pragma("unroll")                                                      \
        for (int kt = 0; kt < 2; ++kt) {                                       \
            _Pragma("unroll")                                                  \
            for (int kc = 0; kc < 2; ++kc)                                     \
                Af[kt][kc] = *(const bf16x8*)((ABUF)                           \
                    + (g * 32 + kt * 16 + li) * 72 + kc * 32 + quad * 8);      \
        }                                                                      \
        f32x4 S[2][2];                                                         \
        _Pragma("unroll")                                                      \
        for (int kt = 0; kt < 2; ++kt) {                                       \
            _Pragma("unroll")                                                  \
            for (int qt = 0; qt < 2; ++qt) {                                   \
                f32x4 z = (f32x4){nKq[qt], nKq[qt], nKq[qt], nKq[qt]};         \
                z = mfma16(Af[kt][0], Qf[qt][0], z);                           \
                S[kt][qt] = mfma16(Af[kt][1], Qf[qt][1], z);                   \
            }                                                                  \
        }                                                                      \
        _Pragma("unroll")                                                      \
        for (int qt = 0; qt < 2; ++qt) {                                       \
            _Pragma("unroll")                                                  \
            for (int kt = 0; kt < 2; ++kt) {                                   \
                bf16x4 pb;                                                     \
                _Pragma("unroll")                                              \
                for (int r = 0; r < 4; ++r) {                                  \
                    float p = __expf(S[kt][qt][r]);                            \
                    lacc[qt] += p;                                             \
                    pb[r] = (__bf16)p;                                         \
                }                                                              \
                *(bf16x4*)((PWp) + qt * 640 + kt * 16) = pb;                   \
            }                                                                  \
        }                                                                      \
    }

// PV phase: P from PRp (written a full phase ago), V from registers
#define PVPH(PRp, Vr)                                                          \
    {                                                                          \
        bf16x8 Ap[2];                                                          \
        _Pragma("unroll")                                                      \
        for (int qt = 0; qt < 2; ++qt)                                         \
            Ap[qt] = *(const bf16x8*)((PRp) + qt * 640);                       \
        _Pragma("unroll")                                                      \
        for (int qt = 0; qt < 2; ++qt) {                                       \
            _Pragma("unroll")                                                  \
            for (int ot = 0; ot < 2; ++ot)                                     \
                Yf[qt][ot] = mfma16(Ap[qt], Vr[ot], Yf[qt][ot]);               \
        }                                                                      \
    }

__global__ __launch_bounds__(256, 4) void k_flash(
    const unsigned short* __restrict__ xT, const unsigned short* __restrict__ gx,
    const float* __restrict__ diag,
    float* __restrict__ ypart, float* __restrict__ lpart)
{
    // LDS: xk0 9216 | xk1 9216 | Pl0 10240 | Pl1 10240 = 38912B
    __shared__ __align__(16) char smem[38912];
    unsigned short* xk0 = (unsigned short*)smem;
    unsigned short* xk1 = (unsigned short*)(smem + 9216);
    unsigned short* Pl0 = (unsigned short*)(smem + 18432);
    unsigned short* Pl1 = (unsigned short*)(smem + 28672);

    const int tid  = threadIdx.x;
    const int wave = tid >> 6, lane = tid & 63;
    const int quad = lane >> 4, li = lane & 15;
    const int g = wave >> 1, qh = wave & 1;
    // ---- XCD-aware remap (bijective over 1024 blocks; R14-verified) ----
    const int bi    = blockIdx.x;
    const int xcd   = bi & 7;
    const int combo = xcd * 2 + ((bi >> 3) & 1);   // 0..15 = (b,kq)
    const int b     = combo >> 2;
    const int kq    = combo & 3;
    const int qtb   = bi >> 4;                     // 0..63
    const int qw  = qtb * 64 + qh * 32;   // wave's first query
    const int u   = tid & 127;            // thread id within key-group

    const unsigned short* xb = xT + (size_t)b * N_ * C_;
    const unsigned short* gb = gx + (size_t)b * CI_ * N_;

    // per-lane softmax shift, negated (MFMA accumulator init)
    float nKq[2];
    #pragma unroll
    for (int qt = 0; qt < 2; ++qt)
        nKq[qt] = -diag[(size_t)b * N_ + qw + qt * 16 + li];

    // Q fragments (B-operand), resident in registers
    bf16x8 Qf[2][2];
    #pragma unroll
    for (int qt = 0; qt < 2; ++qt)
        #pragma unroll
        for (int kc = 0; kc < 2; ++kc)
            Qf[qt][kc] = *(const bf16x8*)(xb + (size_t)(qw + qt * 16 + li) * C_
                                          + kc * 32 + quad * 8);

    f32x4 Yf[2][2];
    #pragma unroll
    for (int qt = 0; qt < 2; ++qt)
        #pragma unroll
        for (int ot = 0; ot < 2; ++ot)
            Yf[qt][ot] = (f32x4){0.f, 0.f, 0.f, 0.f};
    float lacc[2] = {0.f, 0.f};

    const int keybase = kq * 1024 + g * 512;          // this wave's compute keys
    const int gg = tid >> 7;                          // staging group (== g)
    const int sbase = kq * 1024 + gg * 512;           // staged key range base

    // K staging addresses (per thread, 2 x 16B slices of the group's 4KB tile)
    const int cc0 = u * 2,      key0 = cc0 >> 3, cof0 = (cc0 & 7) * 8;
    const int cc1 = u * 2 + 1,  key1 = cc1 >> 3, cof1 = (cc1 & 7) * 8;
    const unsigned short* kSrc0 = xb + (size_t)(sbase + key0) * C_ + cof0;
    const unsigned short* kSrc1 = xb + (size_t)(sbase + key1) * C_ + cof1;
    const int kDst0 = (gg * 32 + key0) * 72 + cof0;
    const int kDst1 = (gg * 32 + key1) * 72 + cof1;

    // V fragment pointers (B-operand layout == gx layout)
    const unsigned short* bBase0 = gb + (size_t)(li) * N_      + keybase + quad * 8;
    const unsigned short* bBase1 = gb + (size_t)(16 + li) * N_ + keybase + quad * 8;

    // P bounce pointers (wave-private, double-buffered)
    unsigned short*       pW0 = Pl0 + (wave * 32 + li) * 40 + quad * 4;
    const unsigned short* pR0 = Pl0 + (wave * 32 + li) * 40 + quad * 8;
    unsigned short*       pW1 = Pl1 + (wave * 32 + li) * 40 + quad * 4;
    const unsigned short* pR1 = Pl1 + (wave * 32 + li) * 40 + quad * 8;

    // ---- prologue ----
    u16x8  kA[2], kB[2];
    bf16x8 vA[2], vB[2];
    KLOAD(kA, 0) VLOAD(vA, 0)
    KLOAD(kB, 1)
    KSTORE(xk0, kA)            // K[0] -> buf0 (vmcnt wait on kA)
    KLOAD(kA, 2)               // K[2] in flight
    __syncthreads();           // buf0 ready

    #pragma unroll 1
    for (int t2 = 0; t2 < 8; ++t2) {
        const int te = 2 * t2;
        // ---- phase te (even): K buf0; QK[te] -> Pl0; PV[te-1] (Pl1, vB) ----
        KSTORE(xk1, kB)                        // K[te+1] -> buf1 (readers done)
        QKPH(xk0, pW0)
        if (t2 > 0) { PVPH(pR1, vB) }          // tile te-1 (odd set)
        { const int nk = (te + 3 < 16) ? te + 3 : 15; KLOAD(kB, nk) }
        VLOAD(vB, te + 1)                      // V for tile te+1 (odd set)
        __syncthreads();                       // buf1 ready
        // ---- phase te+1 (odd): K buf1; QK[te+1] -> Pl1; PV[te] (Pl0, vA) ----
        if (t2 < 7) { KSTORE(xk0, kA) }        // K[te+2] -> buf0
        QKPH(xk1, pW1)
        PVPH(pR0, vA)                          // tile te (even set)
        { const int nk = (te + 4 < 16) ? te + 4 : 15; KLOAD(kA, nk) }
        { const int nv = (te + 2 < 16) ? te + 2 : 15; VLOAD(vA, nv) }
        __syncthreads();                       // buf0 ready
    }
    // ---- drain: PV for tile 15 (odd -> Pl1, vB holds V[15]) ----
    PVPH(pR1, vB)

    // finalize l: sum across quads (keys) -> every lane holds total for query li
    #pragma unroll
    for (int qt = 0; qt < 2; ++qt) {
        lacc[qt] += __shfl_xor(lacc[qt], 16, 64);
        lacc[qt] += __shfl_xor(lacc[qt], 32, 64);
    }

    __syncthreads();   // all waves' P reads done before smem reuse as ym
    // ---- combine the block's 2 key-groups (plain add) -> additive partial ----
    float* ym = (float*)smem;   // [4 wave][32 q][34]: o 0..31 = Y, col 32 = l

    #pragma unroll
    for (int qt = 0; qt < 2; ++qt) {
        #pragma unroll
        for (int ot = 0; ot < 2; ++ot)
            #pragma unroll
            for (int r = 0; r < 4; ++r)
                ym[(wave * 32 + qt * 16 + quad * 4 + r) * 34 + ot * 16 + li] = Yf[qt][ot][r];
        if (quad == 0)
            ym[(wave * 32 + qt * 16 + li) * 34 + 32] = lacc[qt];
    }
    __syncthreads();
    {
        const int q = tid >> 2, og = tid & 3;
        const int qh2 = q >> 5, ql = q & 31;
        const int w0 = qh2, w1 = 2 + qh2;   // same q-half, the two key-groups
        const size_t pbase = (size_t)(b * 64 + qtb) * 4 + kq;
        float* yp = ypart + pbase * 2048 + q * 32;
        #pragma unroll
        for (int j = 0; j < 8; ++j) {
            int o = og * 8 + j;
            yp[o] = ym[(w0 * 32 + ql) * 34 + o] + ym[(w1 * 32 + ql) * 34 + o];
        }
        if (og == 0)
            lpart[pbase * 64 + q] = ym[(w0 * 32 + ql) * 34 + 32]
                                  + ym[(w1 * 32 + ql) * 34 + 32];
    }
}

// ---------------------------------------------------------------------------
// Kernel 3: merge 4 key-quarter partials (plain add) + Wz epilogue + residual.
// Grid: 256 blocks = b x qtile. Block 256 threads.
// ---------------------------------------------------------------------------
__global__ __launch_bounds__(256) void k_merge(
    const float* __restrict__ ypart, const float* __restrict__ lpart,
    const float* __restrict__ x, const float* __restrict__ Wz,
    const float* __restrict__ bz, float* __restrict__ out)
{
    __shared__ float yfin[64][33];
    const int t   = threadIdx.x;
    const int b   = blockIdx.x >> 6;
    const int qtb = blockIdx.x & 63;
    const int q0  = qtb * 64;

    {
        const int q = t >> 2, og = t & 3;
        const size_t pb = (size_t)(b * 64 + qtb) * 4;
        float l = lpart[(pb + 0) * 64 + q] + lpart[(pb + 1) * 64 + q]
                + lpart[(pb + 2) * 64 + q] + lpart[(pb + 3) * 64 + q];
        float inv = 1.f / l;
        #pragma unroll
        for (int j = 0; j < 8; ++j) {
            int o = og * 8 + j;
            float acc = 0.f;
            #pragma unroll
            for (int kq = 0; kq < 4; ++kq)
                acc += ypart[(pb + kq) * 2048 + q * 32 + o];
            yfin[q][o] = acc * inv;
        }
    }
    __syncthreads();
    {
        const int q = t & 63, c0 = t >> 6;
        #pragma unroll
        for (int i = 0; i < 16; ++i) {
            int cout = c0 + i * 4;
            float acc = bz[cout];
            #pragma unroll
            for (int o = 0; o < CI_; ++o)
                acc += Wz[cout * CI_ + o] * yfin[q][o];
            size_t oidx = (size_t)(b * C_ + cout) * N_ + q0 + q;
            out[oidx] = acc + x[oidx];
        }
    }
}

// ---------------------------------------------------------------------------
extern "C" void kernel_launch(void* const* d_in, const int* in_sizes, int n_in,
                              void* d_out, int out_size, void* d_ws, size_t ws_size,
                              hipStream_t stream) {
    (void)in_sizes; (void)n_in; (void)out_size; (void)ws_size;
    const float* x  = (const float*)d_in[0];
    const float* Wg = (const float*)d_in[1];
    const float* bg = (const float*)d_in[2];
    const float* Wz = (const float*)d_in[3];
    const float* bz = (const float*)d_in[4];
    float* out = (float*)d_out;

    // ws layout: xT 2MB | gx 1MB | diag 64KB | ypart 8MB | lpart 256KB (~11.3MB)
    unsigned short* xT = (unsigned short*)d_ws;
    unsigned short* gx = (unsigned short*)((char*)d_ws + 2097152);
    float* diag  = (float*)((char*)d_ws + 3145728);
    float* ypart = (float*)((char*)d_ws + 3211264);
    float* lpart = (float*)((char*)d_ws + 11599872);

    hipLaunchKernelGGL(k_prep,  dim3(B_ * (N_ / 64)),    dim3(256), 0, stream, x, Wg, bg, xT, gx, diag);
    hipLaunchKernelGGL(k_flash, dim3(B_ * 64 * 4),       dim3(256), 0, stream, xT, gx, diag, ypart, lpart);
    hipLaunchKernelGGL(k_merge, dim3(B_ * 64),           dim3(256), 0, stream, ypart, lpart, x, Wz, bz, out);
}